// Round 3
// baseline (12066.381 us; speedup 1.0000x reference)
//
#include <hip/hip_runtime.h>
#include <stdint.h>

#define B_N 8192
#define D_IN 1024
#define D_HID 4096
#define D_LAT 256
#define K_CB 16384

enum { EPI_RELU = 0, EPI_TANH = 1, EPI_RECON = 2, EPI_VQ = 3 };

// C = epilogue(A[M,K] @ B + bias). If BT, Bm is [N,K] row-major (dot over K
// contiguous in both operands); else Bm is [K,N] row-major.
template <int EPI, bool BT>
__global__ __launch_bounds__(256, 2) void gemm_k(
    const float* __restrict__ A, const float* __restrict__ Bm,
    const float* __restrict__ bias, float* __restrict__ C, int M, int N, int K,
    const float* __restrict__ zz, const float* __restrict__ ee,
    unsigned long long* __restrict__ keys, const float* __restrict__ xref,
    double* __restrict__ accums) {
  __shared__ float As[16][128];
  __shared__ float Bs[16][128];
  const int tid = threadIdx.x;
  const int tx = tid & 15, ty = tid >> 4;
  const int m0 = blockIdx.y << 7, n0 = blockIdx.x << 7;

  float acc[8][8];
#pragma unroll
  for (int i = 0; i < 8; ++i)
#pragma unroll
    for (int j = 0; j < 8; ++j) acc[i][j] = 0.0f;

  for (int k0 = 0; k0 < K; k0 += 16) {
    // stage A tile [128 rows x 16 k] transposed -> As[k][m]
#pragma unroll
    for (int r = 0; r < 2; ++r) {
      const int f = tid + (r << 8);
      const int m = f >> 2, kq = (f & 3) << 2;
      const float4 v = *(const float4*)(A + (size_t)(m0 + m) * K + k0 + kq);
      As[kq + 0][m] = v.x;
      As[kq + 1][m] = v.y;
      As[kq + 2][m] = v.z;
      As[kq + 3][m] = v.w;
    }
    if (!BT) {
#pragma unroll
      for (int r = 0; r < 2; ++r) {
        const int f = tid + (r << 8);
        const int k = f >> 5, nq = (f & 31) << 2;
        const float4 v = *(const float4*)(Bm + (size_t)(k0 + k) * N + n0 + nq);
        *(float4*)(&Bs[k][nq]) = v;
      }
    } else {
#pragma unroll
      for (int r = 0; r < 2; ++r) {
        const int f = tid + (r << 8);
        const int n = f >> 2, kq = (f & 3) << 2;
        const float4 v = *(const float4*)(Bm + (size_t)(n0 + n) * K + k0 + kq);
        Bs[kq + 0][n] = v.x;
        Bs[kq + 1][n] = v.y;
        Bs[kq + 2][n] = v.z;
        Bs[kq + 3][n] = v.w;
      }
    }
    __syncthreads();
#pragma unroll
    for (int kk = 0; kk < 16; ++kk) {
      float a[8], b[8];
      *(float4*)(a) = *(const float4*)(&As[kk][ty << 3]);
      *(float4*)(a + 4) = *(const float4*)(&As[kk][(ty << 3) + 4]);
      *(float4*)(b) = *(const float4*)(&Bs[kk][tx << 3]);
      *(float4*)(b + 4) = *(const float4*)(&Bs[kk][(tx << 3) + 4]);
#pragma unroll
      for (int i = 0; i < 8; ++i)
#pragma unroll
        for (int j = 0; j < 8; ++j) acc[i][j] = fmaf(a[i], b[j], acc[i][j]);
    }
    __syncthreads();
  }

  if (EPI == EPI_VQ) {
    // EXACT reference fp32 expression: d = fl(fl(zz+ee) - 2*dot).
    // The coarse quantization at ULP(zz) is intentional: numpy's argmin
    // tie-breaks equal quanta by first index, reproduced via the packed
    // u64 atomicMin key. (2*acc is exact; fp-contract cannot change d.)
    float zr[8];
#pragma unroll
    for (int i = 0; i < 8; ++i) zr[i] = zz[m0 + (ty << 3) + i];
    float ev[8];
    *(float4*)(ev) = *(const float4*)(ee + n0 + (tx << 3));
    *(float4*)(ev + 4) = *(const float4*)(ee + n0 + (tx << 3) + 4);
#pragma unroll
    for (int i = 0; i < 8; ++i) {
      unsigned long long bk = ~0ull;
#pragma unroll
      for (int j = 0; j < 8; ++j) {
        const float t = zr[i] + ev[j];
        const float d = t - 2.0f * acc[i][j];
        unsigned u = __float_as_uint(d);
        u = (u & 0x80000000u) ? ~u : (u | 0x80000000u);
        const unsigned long long key =
            ((unsigned long long)u << 32) | (unsigned)(n0 + (tx << 3) + j);
        bk = key < bk ? key : bk;
      }
#pragma unroll
      for (int s = 1; s <= 8; s <<= 1) {
        const unsigned long long o = __shfl_xor(bk, s);
        if (o < bk) bk = o;
      }
      if (tx == 0) atomicMin(keys + m0 + (ty << 3) + i, bk);
    }
    return;
  }

  float bb[8];
  *(float4*)(bb) = *(const float4*)(bias + n0 + (tx << 3));
  *(float4*)(bb + 4) = *(const float4*)(bias + n0 + (tx << 3) + 4);
  double lsum = 0.0;
#pragma unroll
  for (int i = 0; i < 8; ++i) {
    const int row = m0 + (ty << 3) + i;
    float vrow[8];
#pragma unroll
    for (int j = 0; j < 8; ++j) {
      float v = acc[i][j] + bb[j];
      if (EPI == EPI_RELU) v = fmaxf(v, 0.0f);
      if (EPI == EPI_TANH) v = tanhf(v);
      if (EPI == EPI_RECON) {
        const float xr = xref[(size_t)row * N + n0 + (tx << 3) + j];
        const float df = v - xr;
        lsum += (double)df * (double)df;
      }
      vrow[j] = v;
    }
    *(float4*)(C + (size_t)row * N + n0 + (tx << 3)) = *(float4*)(vrow);
    *(float4*)(C + (size_t)row * N + n0 + (tx << 3) + 4) = *(float4*)(vrow + 4);
  }
  if (EPI == EPI_RECON) {
#pragma unroll
    for (int o = 32; o; o >>= 1) lsum += __shfl_down(lsum, o);
    if ((tid & 63) == 0) atomicAdd(accums + 1, lsum);
  }
}

// out[row] = fp32 sum of squares of 256 contiguous floats (one wave per row).
__global__ void rowsumsq(const float* __restrict__ v, float* __restrict__ out,
                         int rows) {
  const int w = (int)((blockIdx.x * blockDim.x + threadIdx.x) >> 6);
  const int lane = threadIdx.x & 63;
  if (w >= rows) return;
  const float4 x = *(const float4*)(v + (size_t)w * 256 + (lane << 2));
  float s = ((x.x * x.x + x.y * x.y) + x.z * x.z) + x.w * x.w;
#pragma unroll
  for (int o = 32; o; o >>= 1) s += __shfl_down(s, o);
  if (lane == 0) out[w] = s;
}

__global__ void finalize_vq(const unsigned long long* __restrict__ keys,
                            const float* __restrict__ z,
                            const float* __restrict__ cb,
                            float* __restrict__ qst, float* __restrict__ tok,
                            int* __restrict__ counts,
                            double* __restrict__ accums) {
  const int row = (int)((blockIdx.x * blockDim.x + threadIdx.x) >> 6);
  const int lane = threadIdx.x & 63;
  if (row >= B_N) return;
  const int idx = (int)(keys[row] & 0xffffffffull);
  const float4 zv = *(const float4*)(z + (size_t)row * 256 + (lane << 2));
  const float4 evv = *(const float4*)(cb + (size_t)idx * 256 + (lane << 2));
  float4 q;
  double s = 0.0;
  float d;
  d = evv.x - zv.x; q.x = zv.x + d; s += (double)d * (double)d;
  d = evv.y - zv.y; q.y = zv.y + d; s += (double)d * (double)d;
  d = evv.z - zv.z; q.z = zv.z + d; s += (double)d * (double)d;
  d = evv.w - zv.w; q.w = zv.w + d; s += (double)d * (double)d;
  *(float4*)(qst + (size_t)row * 256 + (lane << 2)) = q;
#pragma unroll
  for (int o = 32; o; o >>= 1) s += __shfl_down(s, o);
  if (lane == 0) {
    atomicAdd(accums + 0, s);
    tok[row] = (float)idx;
    atomicAdd(counts + idx, 1);
  }
}

__global__ void finalize_scalars(const int* __restrict__ counts,
                                 const double* __restrict__ accums,
                                 float* __restrict__ outs) {
  __shared__ double red[256];
  double h = 0.0;
  for (int k = threadIdx.x; k < K_CB; k += 256) {
    const float p = (float)counts[k] * (1.0f / 8192.0f);
    const float t = p * logf(p + 1e-10f);
    h += (double)t;
  }
  red[threadIdx.x] = h;
  __syncthreads();
  for (int s = 128; s; s >>= 1) {
    if ((int)threadIdx.x < s) red[threadIdx.x] += red[threadIdx.x + s];
    __syncthreads();
  }
  if (threadIdx.x == 0) {
    const float perp = expf((float)(-red[0]));
    const float m1 = (float)(accums[0] * (1.0 / ((double)B_N * (double)D_LAT)));
    const float vq = m1 + 0.25f * m1;
    const float rl = (float)(accums[1] * (1.0 / ((double)B_N * (double)D_IN)));
    outs[0] = vq;
    outs[1] = rl;
    outs[2] = vq + rl;
    outs[3] = perp;
  }
}

extern "C" void kernel_launch(void* const* d_in, const int* in_sizes, int n_in,
                              void* d_out, int out_size, void* d_ws,
                              size_t ws_size, hipStream_t stream) {
  (void)in_sizes; (void)n_in; (void)out_size;
  const float* x   = (const float*)d_in[0];
  const float* eW1 = (const float*)d_in[1];
  const float* eb1 = (const float*)d_in[2];
  const float* eW2 = (const float*)d_in[3];
  const float* eb2 = (const float*)d_in[4];
  const float* eW3 = (const float*)d_in[5];
  const float* eb3 = (const float*)d_in[6];
  const float* cb  = (const float*)d_in[7];
  const float* dW1 = (const float*)d_in[8];
  const float* db1 = (const float*)d_in[9];
  const float* dW2 = (const float*)d_in[10];
  const float* db2 = (const float*)d_in[11];
  const float* dW3 = (const float*)d_in[12];
  const float* db3 = (const float*)d_in[13];
  float* out = (float*)d_out;

  // Fixed-region layout (byte offsets into d_ws):
  char* ws = (char*)d_ws;
  const size_t OFF_Z      = 0;                       // 8 MiB
  const size_t OFF_QST    = OFF_Z + (size_t)B_N * D_LAT * 4;
  const size_t OFF_EEV    = OFF_QST + (size_t)B_N * D_LAT * 4;
  const size_t OFF_ZZV    = OFF_EEV + (size_t)K_CB * 4;
  const size_t OFF_KEYS   = OFF_ZZV + (size_t)B_N * 4;
  const size_t OFF_COUNTS = OFF_KEYS + (size_t)B_N * 8;
  const size_t OFF_ACC    = OFF_COUNTS + (size_t)K_CB * 4;
  const size_t OFF_H      = OFF_ACC + 256;

  float* z    = (float*)(ws + OFF_Z);
  float* qst  = (float*)(ws + OFF_QST);
  float* eev  = (float*)(ws + OFF_EEV);
  float* zzv  = (float*)(ws + OFF_ZZV);
  unsigned long long* keys = (unsigned long long*)(ws + OFF_KEYS);
  int* counts = (int*)(ws + OFF_COUNTS);
  double* accums = (double*)(ws + OFF_ACC);

  // Pick the largest batch chunk whose two hidden ping-pong buffers fit.
  int chunk = 128;
  for (int c = 2048; c >= 128; c >>= 1) {
    if (OFF_H + 2ull * (size_t)c * D_HID * 4 <= ws_size) { chunk = c; break; }
  }
  float* hA = (float*)(ws + OFF_H);
  float* hB = hA + (size_t)chunk * D_HID;

  float* tok_out = out + (size_t)B_N * D_IN;
  float* scal_out = tok_out + B_N;

  hipMemsetAsync(keys, 0xFF, (size_t)B_N * 8, stream);
  hipMemsetAsync(counts, 0, (size_t)K_CB * 4, stream);
  hipMemsetAsync(accums, 0, 2 * sizeof(double), stream);

  rowsumsq<<<(K_CB * 64) / 256, 256, 0, stream>>>(cb, eev, K_CB);

  // encoder (chunked through hidden buffers)
  for (int c0 = 0; c0 < B_N; c0 += chunk) {
    const dim3 gH(D_HID / 128, chunk / 128);
    gemm_k<EPI_RELU, false><<<gH, 256, 0, stream>>>(
        x + (size_t)c0 * D_IN, eW1, eb1, hA, chunk, D_HID, D_IN,
        nullptr, nullptr, nullptr, nullptr, nullptr);
    gemm_k<EPI_RELU, false><<<gH, 256, 0, stream>>>(
        hA, eW2, eb2, hB, chunk, D_HID, D_HID,
        nullptr, nullptr, nullptr, nullptr, nullptr);
    gemm_k<EPI_TANH, false><<<dim3(D_LAT / 128, chunk / 128), 256, 0, stream>>>(
        hB, eW3, eb3, z + (size_t)c0 * D_LAT, chunk, D_LAT, D_HID,
        nullptr, nullptr, nullptr, nullptr, nullptr);
  }

  rowsumsq<<<(B_N * 64) / 256, 256, 0, stream>>>(z, zzv, B_N);

  // VQ: distances + argmin over full batch
  gemm_k<EPI_VQ, true><<<dim3(K_CB / 128, B_N / 128), 256, 0, stream>>>(
      z, cb, nullptr, nullptr, B_N, K_CB, D_LAT,
      zzv, eev, keys, nullptr, nullptr);
  finalize_vq<<<(B_N * 64) / 256, 256, 0, stream>>>(keys, z, cb, qst, tok_out,
                                                    counts, accums);

  // decoder (chunked)
  for (int c0 = 0; c0 < B_N; c0 += chunk) {
    const dim3 gH(D_HID / 128, chunk / 128);
    gemm_k<EPI_RELU, false><<<gH, 256, 0, stream>>>(
        qst + (size_t)c0 * D_LAT, dW1, db1, hA, chunk, D_HID, D_LAT,
        nullptr, nullptr, nullptr, nullptr, nullptr);
    gemm_k<EPI_RELU, false><<<gH, 256, 0, stream>>>(
        hA, dW2, db2, hB, chunk, D_HID, D_HID,
        nullptr, nullptr, nullptr, nullptr, nullptr);
    gemm_k<EPI_RECON, false><<<dim3(D_IN / 128, chunk / 128), 256, 0, stream>>>(
        hB, dW3, db3, out + (size_t)c0 * D_IN, chunk, D_IN, D_HID,
        nullptr, nullptr, nullptr, x + (size_t)c0 * D_IN, accums);
  }

  finalize_scalars<<<1, 256, 0, stream>>>(counts, accums, scal_out);
}

// Round 4
// 7600.806 us; speedup vs baseline: 1.5875x; 1.5875x over previous
//
#include <hip/hip_runtime.h>
#include <stdint.h>

#define B_N 8192
#define D_IN 1024
#define D_HID 4096
#define D_LAT 256
#define K_CB 16384

typedef __attribute__((ext_vector_type(8))) short bf16x8;
typedef __attribute__((ext_vector_type(4))) float f32x4;

enum { EPI_RELU = 0, EPI_TANH = 1, EPI_RECON = 2, EPI_VQ = 3 };
enum { MEPI_RELU = 0, MEPI_RECON = 1 };

__device__ __forceinline__ unsigned short f2b(float v) {
  unsigned u = __float_as_uint(v);
  u += 0x7fffu + ((u >> 16) & 1u);  // RNE (finite values)
  return (unsigned short)(u >> 16);
}

// ---------------- fp32 VALU GEMM (encoder + VQ). Arithmetic order is
// bit-stable across rounds: per-element fmaf chain over k is fixed. ------
// Micro-tile column/row mapping: thread covers cols {tx*4+j, 64+tx*4+j},
// rows {ty*4+i, 64+ty*4+i} -> LDS b-reads are 16B-stride (2-way, free)
// instead of 32B-stride (4-way conflict).
template <int EPI, bool BT>
__global__ __launch_bounds__(256, 2) void gemm_k(
    const float* __restrict__ A, const float* __restrict__ Bm,
    const float* __restrict__ bias, float* __restrict__ C, int M, int N, int K,
    const float* __restrict__ zz, const float* __restrict__ ee,
    unsigned long long* __restrict__ keys, const float* __restrict__ xref,
    double* __restrict__ accums) {
  __shared__ float As[16][128];
  __shared__ float Bs[16][128];
  const int tid = threadIdx.x;
  const int tx = tid & 15, ty = tid >> 4;
  const int m0 = blockIdx.y << 7, n0 = blockIdx.x << 7;

  float acc[8][8];
#pragma unroll
  for (int i = 0; i < 8; ++i)
#pragma unroll
    for (int j = 0; j < 8; ++j) acc[i][j] = 0.0f;

  for (int k0 = 0; k0 < K; k0 += 16) {
#pragma unroll
    for (int r = 0; r < 2; ++r) {
      const int f = tid + (r << 8);
      const int m = f >> 2, kq = (f & 3) << 2;
      const float4 v = *(const float4*)(A + (size_t)(m0 + m) * K + k0 + kq);
      As[kq + 0][m] = v.x;
      As[kq + 1][m] = v.y;
      As[kq + 2][m] = v.z;
      As[kq + 3][m] = v.w;
    }
    if (!BT) {
#pragma unroll
      for (int r = 0; r < 2; ++r) {
        const int f = tid + (r << 8);
        const int k = f >> 5, nq = (f & 31) << 2;
        const float4 v = *(const float4*)(Bm + (size_t)(k0 + k) * N + n0 + nq);
        *(float4*)(&Bs[k][nq]) = v;
      }
    } else {
#pragma unroll
      for (int r = 0; r < 2; ++r) {
        const int f = tid + (r << 8);
        const int n = f >> 2, kq = (f & 3) << 2;
        const float4 v = *(const float4*)(Bm + (size_t)(n0 + n) * K + k0 + kq);
        Bs[kq + 0][n] = v.x;
        Bs[kq + 1][n] = v.y;
        Bs[kq + 2][n] = v.z;
        Bs[kq + 3][n] = v.w;
      }
    }
    __syncthreads();
#pragma unroll
    for (int kk = 0; kk < 16; ++kk) {
      float a[8], b[8];
      *(float4*)(a) = *(const float4*)(&As[kk][ty << 2]);
      *(float4*)(a + 4) = *(const float4*)(&As[kk][64 + (ty << 2)]);
      *(float4*)(b) = *(const float4*)(&Bs[kk][tx << 2]);
      *(float4*)(b + 4) = *(const float4*)(&Bs[kk][64 + (tx << 2)]);
#pragma unroll
      for (int i = 0; i < 8; ++i)
#pragma unroll
        for (int j = 0; j < 8; ++j) acc[i][j] = fmaf(a[i], b[j], acc[i][j]);
    }
    __syncthreads();
  }

  if (EPI == EPI_VQ) {
    // EXACT reference fp32 expression: d = fl(fl(zz+ee) - 2*dot), first-index
    // tie-break via packed u64 atomicMin.
    float zr[8];
#pragma unroll
    for (int i = 0; i < 8; ++i)
      zr[i] = zz[m0 + ((i < 4) ? (ty << 2) + i : 64 + (ty << 2) + i - 4)];
    float ev[8];
    *(float4*)(ev) = *(const float4*)(ee + n0 + (tx << 2));
    *(float4*)(ev + 4) = *(const float4*)(ee + n0 + 64 + (tx << 2));
#pragma unroll
    for (int i = 0; i < 8; ++i) {
      unsigned long long bk = ~0ull;
#pragma unroll
      for (int j = 0; j < 8; ++j) {
        const int col = n0 + ((j < 4) ? (tx << 2) + j : 64 + (tx << 2) + j - 4);
        const float t = zr[i] + ev[j];
        const float d = t - 2.0f * acc[i][j];
        unsigned u = __float_as_uint(d);
        u = (u & 0x80000000u) ? ~u : (u | 0x80000000u);
        const unsigned long long key = ((unsigned long long)u << 32) | (unsigned)col;
        bk = key < bk ? key : bk;
      }
#pragma unroll
      for (int s = 1; s <= 8; s <<= 1) {
        const unsigned long long o = __shfl_xor(bk, s);
        if (o < bk) bk = o;
      }
      if (tx == 0) {
        const int row = m0 + ((i < 4) ? (ty << 2) + i : 64 + (ty << 2) + i - 4);
        atomicMin(keys + row, bk);
      }
    }
    return;
  }

  float bb[8];
  *(float4*)(bb) = *(const float4*)(bias + n0 + (tx << 2));
  *(float4*)(bb + 4) = *(const float4*)(bias + n0 + 64 + (tx << 2));
  double lsum = 0.0;
#pragma unroll
  for (int i = 0; i < 8; ++i) {
    const int row = m0 + ((i < 4) ? (ty << 2) + i : 64 + (ty << 2) + i - 4);
    float vrow[8];
#pragma unroll
    for (int j = 0; j < 8; ++j) {
      float v = acc[i][j] + bb[j];
      if (EPI == EPI_RELU) v = fmaxf(v, 0.0f);
      if (EPI == EPI_TANH) v = tanhf(v);
      if (EPI == EPI_RECON) {
        const int col = n0 + ((j < 4) ? (tx << 2) + j : 64 + (tx << 2) + j - 4);
        const float xr = xref[(size_t)row * N + col];
        const float df = v - xr;
        lsum += (double)df * (double)df;
      }
      vrow[j] = v;
    }
    *(float4*)(C + (size_t)row * N + n0 + (tx << 2)) = *(float4*)(vrow);
    *(float4*)(C + (size_t)row * N + n0 + 64 + (tx << 2)) = *(float4*)(vrow + 4);
  }
  if (EPI == EPI_RECON) {
#pragma unroll
    for (int o = 32; o; o >>= 1) lsum += __shfl_down(lsum, o);
    if ((tid & 63) == 0) atomicAdd(accums + 1, lsum);
  }
}

// ---------------- bf16 MFMA GEMM (decoder). A [M][K] bf16, Bt [N][K] bf16,
// fp32 accum; EPI RELU -> bf16 C, RECON -> fp32 C + loss. ----------------
template <int EPI>
__global__ __launch_bounds__(256, 2) void mgemm_k(
    const unsigned short* __restrict__ A, const unsigned short* __restrict__ Bt,
    const float* __restrict__ bias, void* __restrict__ Cout, int M, int N,
    int K, const float* __restrict__ xref, double* __restrict__ accums) {
  // frag-ready LDS: elem idx (m,kc,k7) -> kc*1024 + ((m ^ kc)*8) + k7
  __shared__ __align__(16) unsigned short As[4096];
  __shared__ __align__(16) unsigned short Bs[4096];
  const int tid = threadIdx.x;
  const int w = tid >> 6, l = tid & 63;
  const int wr = w >> 1, wc = w & 1;
  const int g = l >> 4, tx = l & 15;
  const int m0 = blockIdx.y << 7, n0 = blockIdx.x << 7;

  f32x4 acc[4][4];
#pragma unroll
  for (int i = 0; i < 4; ++i)
#pragma unroll
    for (int j = 0; j < 4; ++j) acc[i][j] = (f32x4)0.0f;

  for (int k0 = 0; k0 < K; k0 += 32) {
#pragma unroll
    for (int r = 0; r < 2; ++r) {
      const int c = (r << 8) + tid;
      const int mm = c >> 2, kc = c & 3;
      const uint4 va = *(const uint4*)(A + (size_t)(m0 + mm) * K + k0 + (kc << 3));
      *(uint4*)&As[(kc << 10) + ((mm ^ kc) << 3)] = va;
      const uint4 vb = *(const uint4*)(Bt + (size_t)(n0 + mm) * K + k0 + (kc << 3));
      *(uint4*)&Bs[(kc << 10) + ((mm ^ kc) << 3)] = vb;
    }
    __syncthreads();
    bf16x8 af[4], bfv[4];
#pragma unroll
    for (int f = 0; f < 4; ++f) {
      const int ma = (wr << 6) + (f << 4) + tx;
      af[f] = *(const bf16x8*)&As[(g << 10) + ((ma ^ g) << 3)];
      const int nb = (wc << 6) + (f << 4) + tx;
      bfv[f] = *(const bf16x8*)&Bs[(g << 10) + ((nb ^ g) << 3)];
    }
#pragma unroll
    for (int fm = 0; fm < 4; ++fm)
#pragma unroll
      for (int fn = 0; fn < 4; ++fn)
        acc[fm][fn] = __builtin_amdgcn_mfma_f32_16x16x32_bf16(
            af[fm], bfv[fn], acc[fm][fn], 0, 0, 0);
    __syncthreads();
  }

  double lsum = 0.0;
#pragma unroll
  for (int fm = 0; fm < 4; ++fm) {
    const int row0 = m0 + (wr << 6) + (fm << 4) + (g << 2);
#pragma unroll
    for (int fn = 0; fn < 4; ++fn) {
      const int col = n0 + (wc << 6) + (fn << 4) + tx;
      const float bb = bias[col];
#pragma unroll
      for (int r = 0; r < 4; ++r) {
        float v = acc[fm][fn][r] + bb;
        if (EPI == MEPI_RELU) {
          v = fmaxf(v, 0.0f);
          ((unsigned short*)Cout)[(size_t)(row0 + r) * N + col] = f2b(v);
        } else {
          const float xr = xref[(size_t)(row0 + r) * N + col];
          const float df = v - xr;
          lsum += (double)df * (double)df;
          ((float*)Cout)[(size_t)(row0 + r) * N + col] = v;
        }
      }
    }
  }
  if (EPI == MEPI_RECON) {
#pragma unroll
    for (int o = 32; o; o >>= 1) lsum += __shfl_down(lsum, o);
    if (l == 0) atomicAdd(accums + 1, lsum);
  }
}

// transpose-cast fp32 [K][N] -> bf16 [N][K]
__global__ void castT_k(const float* __restrict__ W,
                        unsigned short* __restrict__ out, int K, int N) {
  __shared__ float t[32][33];
  const int tx = threadIdx.x & 31, ty4 = threadIdx.x >> 5;
  const int nb = blockIdx.x << 5, kb = blockIdx.y << 5;
#pragma unroll
  for (int r = 0; r < 4; ++r) {
    const int k = (ty4 << 2) + r;
    t[k][tx] = W[(size_t)(kb + k) * N + nb + tx];
  }
  __syncthreads();
#pragma unroll
  for (int r = 0; r < 4; ++r) {
    const int n = (ty4 << 2) + r;
    out[(size_t)(nb + n) * K + kb + tx] = f2b(t[tx][n]);
  }
}

__global__ void rowsumsq(const float* __restrict__ v, float* __restrict__ out,
                         int rows) {
  const int w = (int)((blockIdx.x * blockDim.x + threadIdx.x) >> 6);
  const int lane = threadIdx.x & 63;
  if (w >= rows) return;
  const float4 x = *(const float4*)(v + (size_t)w * 256 + (lane << 2));
  float s = ((x.x * x.x + x.y * x.y) + x.z * x.z) + x.w * x.w;
#pragma unroll
  for (int o = 32; o; o >>= 1) s += __shfl_down(s, o);
  if (lane == 0) out[w] = s;
}

__global__ void finalize_vq(const unsigned long long* __restrict__ keys,
                            const float* __restrict__ z,
                            const float* __restrict__ cb,
                            unsigned short* __restrict__ qst_bf,
                            float* __restrict__ tok, int* __restrict__ counts,
                            double* __restrict__ accums) {
  const int row = (int)((blockIdx.x * blockDim.x + threadIdx.x) >> 6);
  const int lane = threadIdx.x & 63;
  if (row >= B_N) return;
  const int idx = (int)(keys[row] & 0xffffffffull);
  const float4 zv = *(const float4*)(z + (size_t)row * 256 + (lane << 2));
  const float4 evv = *(const float4*)(cb + (size_t)idx * 256 + (lane << 2));
  float4 q;
  double s = 0.0;
  float d;
  d = evv.x - zv.x; q.x = zv.x + d; s += (double)d * (double)d;
  d = evv.y - zv.y; q.y = zv.y + d; s += (double)d * (double)d;
  d = evv.z - zv.z; q.z = zv.z + d; s += (double)d * (double)d;
  d = evv.w - zv.w; q.w = zv.w + d; s += (double)d * (double)d;
  ushort4 qb;
  qb.x = f2b(q.x); qb.y = f2b(q.y); qb.z = f2b(q.z); qb.w = f2b(q.w);
  *(ushort4*)(qst_bf + (size_t)row * 256 + (lane << 2)) = qb;
#pragma unroll
  for (int o = 32; o; o >>= 1) s += __shfl_down(s, o);
  if (lane == 0) {
    atomicAdd(accums + 0, s);
    tok[row] = (float)idx;
    atomicAdd(counts + idx, 1);
  }
}

__global__ void finalize_scalars(const int* __restrict__ counts,
                                 const double* __restrict__ accums,
                                 float* __restrict__ outs) {
  __shared__ double red[256];
  double h = 0.0;
  for (int k = threadIdx.x; k < K_CB; k += 256) {
    const float p = (float)counts[k] * (1.0f / 8192.0f);
    const float t = p * logf(p + 1e-10f);
    h += (double)t;
  }
  red[threadIdx.x] = h;
  __syncthreads();
  for (int s = 128; s; s >>= 1) {
    if ((int)threadIdx.x < s) red[threadIdx.x] += red[threadIdx.x + s];
    __syncthreads();
  }
  if (threadIdx.x == 0) {
    const float perp = expf((float)(-red[0]));
    const float m1 = (float)(accums[0] * (1.0 / ((double)B_N * (double)D_LAT)));
    const float vq = m1 + 0.25f * m1;
    const float rl = (float)(accums[1] * (1.0 / ((double)B_N * (double)D_IN)));
    outs[0] = vq;
    outs[1] = rl;
    outs[2] = vq + rl;
    outs[3] = perp;
  }
}

extern "C" void kernel_launch(void* const* d_in, const int* in_sizes, int n_in,
                              void* d_out, int out_size, void* d_ws,
                              size_t ws_size, hipStream_t stream) {
  (void)in_sizes; (void)n_in; (void)out_size;
  const float* x   = (const float*)d_in[0];
  const float* eW1 = (const float*)d_in[1];
  const float* eb1 = (const float*)d_in[2];
  const float* eW2 = (const float*)d_in[3];
  const float* eb2 = (const float*)d_in[4];
  const float* eW3 = (const float*)d_in[5];
  const float* eb3 = (const float*)d_in[6];
  const float* cb  = (const float*)d_in[7];
  const float* dW1 = (const float*)d_in[8];
  const float* db1 = (const float*)d_in[9];
  const float* dW2 = (const float*)d_in[10];
  const float* db2 = (const float*)d_in[11];
  const float* dW3 = (const float*)d_in[12];
  const float* db3 = (const float*)d_in[13];
  float* out = (float*)d_out;

  char* ws = (char*)d_ws;
  const size_t OFF_Z      = 0;
  const size_t OFF_EEV    = OFF_Z + (size_t)B_N * D_LAT * 4;      // z 8MB
  const size_t OFF_ZZV    = OFF_EEV + (size_t)K_CB * 4;
  const size_t OFF_KEYS   = OFF_ZZV + (size_t)B_N * 4;
  const size_t OFF_COUNTS = OFF_KEYS + (size_t)B_N * 8;
  const size_t OFF_ACC    = OFF_COUNTS + (size_t)K_CB * 4;
  const size_t OFF_QB     = OFF_ACC + 256;                        // qst bf16 4MB
  const size_t OFF_H      = OFF_QB + (size_t)B_N * D_LAT * 2;

  float* z    = (float*)(ws + OFF_Z);
  float* eev  = (float*)(ws + OFF_EEV);
  float* zzv  = (float*)(ws + OFF_ZZV);
  unsigned long long* keys = (unsigned long long*)(ws + OFF_KEYS);
  int* counts = (int*)(ws + OFF_COUNTS);
  double* accums = (double*)(ws + OFF_ACC);
  unsigned short* qst_bf = (unsigned short*)(ws + OFF_QB);

  // encoder phase buffers (fp32 ping-pong), reused later by decoder
  int c_enc = 128;
  for (int c = 2048; c >= 128; c >>= 1)
    if (OFF_H + 2ull * c * D_HID * 4 <= ws_size) { c_enc = c; break; }
  float* hA = (float*)(ws + OFF_H);
  float* hB = hA + (size_t)c_enc * D_HID;

  // decoder phase buffers (bf16 weights + ping-pong), same region
  const size_t SZ_WB1 = (size_t)D_HID * D_LAT * 2;   // 2MB
  const size_t SZ_WB2 = (size_t)D_HID * D_HID * 2;   // 32MB
  const size_t SZ_WB3 = (size_t)D_IN * D_HID * 2;    // 8MB
  const size_t OFF_DECH = OFF_H + SZ_WB1 + SZ_WB2 + SZ_WB3;
  int c_dec = 128;
  for (int c = 2048; c >= 128; c >>= 1)
    if (OFF_DECH + 2ull * c * D_HID * 2 <= ws_size) { c_dec = c; break; }
  unsigned short* wB1 = (unsigned short*)(ws + OFF_H);
  unsigned short* wB2 = (unsigned short*)(ws + OFF_H + SZ_WB1);
  unsigned short* wB3 = (unsigned short*)(ws + OFF_H + SZ_WB1 + SZ_WB2);
  unsigned short* hbfA = (unsigned short*)(ws + OFF_DECH);
  unsigned short* hbfB = hbfA + (size_t)c_dec * D_HID;

  float* tok_out = out + (size_t)B_N * D_IN;
  float* scal_out = tok_out + B_N;

  hipMemsetAsync(keys, 0xFF, (size_t)B_N * 8, stream);
  hipMemsetAsync(counts, 0, (size_t)K_CB * 4, stream);
  hipMemsetAsync(accums, 0, 2 * sizeof(double), stream);

  rowsumsq<<<(K_CB * 64) / 256, 256, 0, stream>>>(cb, eev, K_CB);

  // ---- encoder (fp32, bit-stable) ----
  for (int c0 = 0; c0 < B_N; c0 += c_enc) {
    const dim3 gH(D_HID / 128, c_enc / 128);
    gemm_k<EPI_RELU, false><<<gH, 256, 0, stream>>>(
        x + (size_t)c0 * D_IN, eW1, eb1, hA, c_enc, D_HID, D_IN,
        nullptr, nullptr, nullptr, nullptr, nullptr);
    gemm_k<EPI_RELU, false><<<gH, 256, 0, stream>>>(
        hA, eW2, eb2, hB, c_enc, D_HID, D_HID,
        nullptr, nullptr, nullptr, nullptr, nullptr);
    gemm_k<EPI_TANH, false><<<dim3(D_LAT / 128, c_enc / 128), 256, 0, stream>>>(
        hB, eW3, eb3, z + (size_t)c0 * D_LAT, c_enc, D_LAT, D_HID,
        nullptr, nullptr, nullptr, nullptr, nullptr);
  }

  rowsumsq<<<(B_N * 64) / 256, 256, 0, stream>>>(z, zzv, B_N);

  // ---- VQ (fp32, exact reference expression) ----
  gemm_k<EPI_VQ, true><<<dim3(K_CB / 128, B_N / 128), 256, 0, stream>>>(
      z, cb, nullptr, nullptr, B_N, K_CB, D_LAT, zzv, eev, keys, nullptr,
      nullptr);
  finalize_vq<<<(B_N * 64) / 256, 256, 0, stream>>>(keys, z, cb, qst_bf,
                                                    tok_out, counts, accums);

  // ---- decoder weight transpose-casts (region H now free) ----
  castT_k<<<dim3(D_HID / 32, D_LAT / 32), 256, 0, stream>>>(dW1, wB1, D_LAT, D_HID);
  castT_k<<<dim3(D_HID / 32, D_HID / 32), 256, 0, stream>>>(dW2, wB2, D_HID, D_HID);
  castT_k<<<dim3(D_IN / 32, D_HID / 32), 256, 0, stream>>>(dW3, wB3, D_HID, D_IN);

  // ---- decoder (bf16 MFMA) ----
  for (int c0 = 0; c0 < B_N; c0 += c_dec) {
    const dim3 gH(D_HID / 128, c_dec / 128);
    mgemm_k<MEPI_RELU><<<gH, 256, 0, stream>>>(
        qst_bf + (size_t)c0 * D_LAT, wB1, db1, hbfA, c_dec, D_HID, D_LAT,
        nullptr, nullptr);
    mgemm_k<MEPI_RELU><<<gH, 256, 0, stream>>>(
        hbfA, wB2, db2, hbfB, c_dec, D_HID, D_HID, nullptr, nullptr);
    mgemm_k<MEPI_RECON><<<dim3(D_IN / 128, c_dec / 128), 256, 0, stream>>>(
        hbfB, wB3, db3, out + (size_t)c0 * D_IN, c_dec, D_IN, D_HID,
        x + (size_t)c0 * D_IN, accums);
  }

  finalize_scalars<<<1, 256, 0, stream>>>(counts, accums, scal_out);
}